// Round 6
// baseline (862.911 us; speedup 1.0000x reference)
//
#include <hip/hip_runtime.h>
#include <hip/hip_bf16.h>

#define N_NODES 19000
#define N_EDGES 600000
#define BATCH   4096
#define GNN_D   256
#define H_D     512
#define MID_D   2048
#define L_N     6
#define C_N     3
#define R_D     512
#define G_N     6640
#define LN_EPS  1e-5f
#define MAXDEG  128

typedef __attribute__((ext_vector_type(8))) short short8;
typedef __attribute__((ext_vector_type(4))) float f32x4;
typedef __hip_bfloat16 bf16;

// ---------------- merged weight conversion (7 dsts, 1 launch) ----------------
// f4-index segments, cumulative offsets
#define SEG0 32768                    // w_in   512*256/4
#define SEG1 (SEG0 + 1572864)         // fc1    6*2048*512/4
#define SEG2 (SEG1 + 1572864)         // fc2
#define SEG3 (SEG2 + 196608)          // wbil   3*512*512/4
#define SEG4 (SEG3 + 849920)          // gene   6640*512/4
#define SEG5 (SEG4 + 16384)           // wpost  256*256/4
#define SEG6 (SEG5 + 32768)           // wrn    256*512/4
#define CONV_TOT SEG6

__global__ void convert_weights_kernel(
    const float* __restrict__ w_in, const float* __restrict__ fc1,
    const float* __restrict__ fc2, const float* __restrict__ wbil,
    const float* __restrict__ gene, const float* __restrict__ wpost,
    const float* __restrict__ wroot, const float* __restrict__ wneigh,
    bf16* __restrict__ o_win, bf16* __restrict__ o_fc1, bf16* __restrict__ o_fc2,
    bf16* __restrict__ o_wbil, bf16* __restrict__ o_gene, bf16* __restrict__ o_wpost,
    bf16* __restrict__ o_wrn) {
  int i = blockIdx.x * blockDim.x + threadIdx.x;
  if (i >= CONV_TOT) return;
  const float* src;
  bf16* dst;
  if (i < SEG0)      { src = w_in  + (size_t)i * 4;            dst = o_win  + (size_t)i * 4; }
  else if (i < SEG1) { size_t j = i - SEG0; src = fc1  + j * 4; dst = o_fc1  + j * 4; }
  else if (i < SEG2) { size_t j = i - SEG1; src = fc2  + j * 4; dst = o_fc2  + j * 4; }
  else if (i < SEG3) { size_t j = i - SEG2; src = wbil + j * 4; dst = o_wbil + j * 4; }
  else if (i < SEG4) { size_t j = i - SEG3; src = gene + j * 4; dst = o_gene + j * 4; }
  else if (i < SEG5) { size_t j = i - SEG4; src = wpost+ j * 4; dst = o_wpost+ j * 4; }
  else {  // wrn: [256][512] = [w_root | w_neigh]
    int j = i - SEG5;
    int base = j * 4;
    int n = base >> 9;
    int k = base & 511;
    src = (k < GNN_D) ? (wroot + (size_t)n * GNN_D + k)
                      : (wneigh + (size_t)n * GNN_D + (k - GNN_D));
    dst = o_wrn + base;
  }
  float4 v = *(const float4*)src;
  dst[0] = __float2bfloat16(v.x);
  dst[1] = __float2bfloat16(v.y);
  dst[2] = __float2bfloat16(v.z);
  dst[3] = __float2bfloat16(v.w);
}

// ---------------- graph compaction kernels (unchanged, proven) ----------------

__global__ void init_meta_kernel(int* __restrict__ flags, int* __restrict__ cursor,
                                 int* __restrict__ nuniq) {
  int i = blockIdx.x * blockDim.x + threadIdx.x;
  if (i < N_NODES) flags[i] = 0;
  if (i < BATCH) cursor[i] = 0;
  if (i == 0) *nuniq = 0;
}

__global__ void mark_needed_kernel(const int* __restrict__ idx, int* __restrict__ flags) {
  int i = blockIdx.x * blockDim.x + threadIdx.x;
  if (i < BATCH) {
    int id = idx[i];
    if (id >= 0) flags[id] = 1;
  }
}

__global__ void assign_slots_kernel(const int* __restrict__ flags, int* __restrict__ slot,
                                    int* __restrict__ uniq, int* __restrict__ nuniq) {
  int i = blockIdx.x * blockDim.x + threadIdx.x;
  if (i >= N_NODES) return;
  if (flags[i]) {
    int s = atomicAdd(nuniq, 1);
    slot[i] = s;
    uniq[s] = i;
  }
}

__global__ __launch_bounds__(256) void fill_edges_kernel(
    const int* __restrict__ ei, const float* __restrict__ ew,
    const int* __restrict__ flags, const int* __restrict__ slot,
    int* __restrict__ cursor, int* __restrict__ el_src, float* __restrict__ el_w) {
  int e = blockIdx.x * blockDim.x + threadIdx.x;
  if (e >= N_EDGES) return;
  int dst = ei[N_EDGES + e];
  if (!flags[dst]) return;
  int s = slot[dst];
  int p = atomicAdd(&cursor[s], 1);
  if (p < MAXDEG) {
    el_src[s * MAXDEG + p] = ei[e];
    el_w[s * MAXDEG + p] = ew[e];
  }
}

__global__ __launch_bounds__(256) void gather_nodes_kernel(
    const float* __restrict__ cache, const int* __restrict__ uniq,
    const int* __restrict__ cursor, const int* __restrict__ nuniq,
    const int* __restrict__ el_src, const float* __restrict__ el_w,
    bf16* __restrict__ compact2) {
  int s = blockIdx.x, t = threadIdx.x;
  bf16* row = compact2 + (size_t)s * (2 * GNN_D);
  if (s >= *nuniq) {
    row[t] = __float2bfloat16(0.f);
    row[GNN_D + t] = __float2bfloat16(0.f);
    return;
  }
  row[t] = __float2bfloat16(cache[(size_t)uniq[s] * GNN_D + t]);
  int deg = cursor[s];
  deg = (deg < MAXDEG) ? deg : MAXDEG;
  float acc = 0.f;
  for (int e = 0; e < deg; ++e) {
    int src = el_src[s * MAXDEG + e];
    float w = el_w[s * MAXDEG + e];
    acc += cache[(size_t)src * GNN_D + t] * w;
  }
  row[GNN_D + t] = __float2bfloat16(acc);
}

__global__ __launch_bounds__(256) void gather_ln_kernel(
    const float* __restrict__ embc, const int* __restrict__ slot,
    const float* __restrict__ fallback, const int* __restrict__ idx,
    const float* __restrict__ scale, const float* __restrict__ bias,
    bf16* __restrict__ out) {
  int b = blockIdx.x, t = threadIdx.x;
  int id = idx[b];
  float v = (id >= 0) ? embc[(size_t)slot[id] * GNN_D + t] : fallback[t];
  float s = v, q = v * v;
#pragma unroll
  for (int o = 32; o > 0; o >>= 1) { s += __shfl_down(s, o); q += __shfl_down(q, o); }
  __shared__ float ls[4], lq[4];
  int wv = t >> 6, ln = t & 63;
  if (ln == 0) { ls[wv] = s; lq[wv] = q; }
  __syncthreads();
  s = ls[0] + ls[1] + ls[2] + ls[3];
  q = lq[0] + lq[1] + lq[2] + lq[3];
  float mu = s * (1.f / GNN_D);
  float var = q * (1.f / GNN_D) - mu * mu;
  float r = rsqrtf(var + LN_EPS);
  out[(size_t)b * GNN_D + t] = __float2bfloat16((v - mu) * r * scale[t] + bias[t]);
}

__global__ __launch_bounds__(256) void ln512_kernel(
    const float* __restrict__ x, const float* __restrict__ scale,
    const float* __restrict__ bias, bf16* __restrict__ out) {
  int b = blockIdx.x, t = threadIdx.x;
  const float* xr = x + (size_t)b * H_D;
  float v0 = xr[t];
  float v1 = xr[256 + t];
  float s = v0 + v1, q = v0 * v0 + v1 * v1;
#pragma unroll
  for (int o = 32; o > 0; o >>= 1) { s += __shfl_down(s, o); q += __shfl_down(q, o); }
  __shared__ float ls[4], lq[4];
  int wv = t >> 6, ln = t & 63;
  if (ln == 0) { ls[wv] = s; lq[wv] = q; }
  __syncthreads();
  s = ls[0] + ls[1] + ls[2] + ls[3];
  q = lq[0] + lq[1] + lq[2] + lq[3];
  float mu = s * (1.f / H_D);
  float var = q * (1.f / H_D) - mu * mu;
  float r = rsqrtf(var + LN_EPS);
  bf16* orow = out + (size_t)b * H_D;
  orow[t]       = __float2bfloat16((v0 - mu) * r * scale[t]       + bias[t]);
  orow[256 + t] = __float2bfloat16((v1 - mu) * r * scale[256 + t] + bias[256 + t]);
}

__device__ inline float gelu_exact(float x) {
  return 0.5f * x * (1.f + erff(x * 0.70710678118654752f));
}

// ------ B-panel-resident streaming MFMA GEMM: C = act(A @ W^T [+bias] [+addC]) ------
// Stage W-panel (64 cols x KCHUNK) in LDS ONCE per K-chunk; stream A fragments from
// global (L2) into registers. NO barriers in the k-loop -> MFMA-only regime.
// Block: (NWM*64) x 64. 4 waves: wm = wid%NWM rows, wn = wid/NWM col-halves.
// NWM=4,NWN=1: 256x64 block (einsum/fc1/bilinear/proj/graph); NWM=2,NWN=2: 128x64 (fc2).
// Fragment math & C/D mapping identical to the round-2..4 verified kernel.

template <int NWM, int NWN, int KCHUNK, int ACT, int OUT_BF16, int ADDC, int BIAS,
          int HBF, int SWZ>
__global__ __launch_bounds__(256) void gemm_bpanel_kernel(
    const bf16* __restrict__ A, const bf16* __restrict__ W,
    const float* __restrict__ bias, const float* __restrict__ addC,
    void* __restrict__ Cout, bf16* __restrict__ out2,
    int M, int N, int K, int gx) {
  constexpr int BM = NWM * 64;
  constexpr int NF_N = 4 / NWN;          // 16-wide n-frags per wave
  constexpr int LDB = KCHUNK + 8;        // pad: 16B-aligned rows, ~2-way banks
  __shared__ __align__(16) bf16 sB[64 * LDB];

  const int tid = threadIdx.x;
  const int lane = tid & 63;
  const int wid = tid >> 6;
  const int wm = wid % NWM, wn = wid / NWM;

  int bidx, bidy;
  if (SWZ) {
    int nwg = gridDim.x;
    int bid = blockIdx.x;
    int q = nwg >> 3, r = nwg & 7;
    int xcd = bid & 7, orig = bid >> 3;
    int swz = (xcd < r ? xcd * (q + 1) : r * (q + 1) + (xcd - r) * q) + orig;
    bidx = swz % gx;
    bidy = swz / gx;
  } else {
    bidx = blockIdx.x;
    bidy = blockIdx.y;
  }
  const int bm = bidx * BM, bn = bidy * 64;

  const int rbase = lane & 15;
  const int g = lane >> 4;

  // A row base pointers for the 4 m-frags (include k-group offset g*8)
  const bf16* aptr[4];
#pragma unroll
  for (int m = 0; m < 4; ++m) {
    int r = bm + wm * 64 + m * 16 + rbase;
    r = (r < M) ? r : (M - 1);
    aptr[m] = A + (size_t)r * K + g * 8;
  }

  f32x4 acc[4][NF_N];
#pragma unroll
  for (int m = 0; m < 4; ++m)
#pragma unroll
    for (int n = 0; n < NF_N; ++n) acc[m][n] = (f32x4){0.f, 0.f, 0.f, 0.f};

  const int bcol = wn * (NF_N * 16);     // wave's col offset within the 64-panel
  const int NCH = K / KCHUNK;

  for (int ch = 0; ch < NCH; ++ch) {
    if (ch) __syncthreads();             // prior chunk's reads complete
    // ---- stage panel: 64 rows x KCHUNK, per-thread 16B chunks ----
    constexpr int ITERS = (64 * KCHUNK) / (256 * 8);
#pragma unroll
    for (int it = 0; it < ITERS; ++it) {
      int idx = it * 256 + tid;
      int row = idx / (KCHUNK / 8);
      int kk = (idx % (KCHUNK / 8)) * 8;
      int br = bn + row;
      br = (br < N) ? br : (N - 1);
      *(short8*)(sB + row * LDB + kk) =
          *(const short8*)(W + (size_t)br * K + (size_t)ch * KCHUNK + kk);
    }
    __syncthreads();

    // ---- barrier-free k-loop, register double-buffered frags ----
    short8 afC[4], bfC[NF_N];
#pragma unroll
    for (int m = 0; m < 4; ++m)
      afC[m] = *(const short8*)(aptr[m] + (size_t)ch * KCHUNK);
#pragma unroll
    for (int n = 0; n < NF_N; ++n)
      bfC[n] = *(const short8*)(sB + (bcol + n * 16 + rbase) * LDB + g * 8);

#pragma unroll 2
    for (int kk = 0; kk < KCHUNK; kk += 32) {
      short8 afN[4], bfN[NF_N];
      if (kk + 32 < KCHUNK) {
#pragma unroll
        for (int m = 0; m < 4; ++m)
          afN[m] = *(const short8*)(aptr[m] + (size_t)ch * KCHUNK + kk + 32);
#pragma unroll
        for (int n = 0; n < NF_N; ++n)
          bfN[n] = *(const short8*)(sB + (bcol + n * 16 + rbase) * LDB + kk + 32 + g * 8);
      }
#pragma unroll
      for (int m = 0; m < 4; ++m)
#pragma unroll
        for (int n = 0; n < NF_N; ++n)
          acc[m][n] = __builtin_amdgcn_mfma_f32_16x16x32_bf16(afC[m], bfC[n], acc[m][n], 0, 0, 0);
#pragma unroll
      for (int m = 0; m < 4; ++m) afC[m] = afN[m];
#pragma unroll
      for (int n = 0; n < NF_N; ++n) bfC[n] = bfN[n];
    }
  }

  // epilogue: C/D frag mapping col=lane&15, row=(lane>>4)*4+reg  [m89-verified]
  const int rb = (lane >> 4) * 4;
  const int cb = lane & 15;
#pragma unroll
  for (int m = 0; m < 4; ++m) {
#pragma unroll
    for (int n = 0; n < NF_N; ++n) {
      int col = bn + bcol + n * 16 + cb;
      if (col >= N) continue;
      int row0 = bm + wm * 64 + m * 16 + rb;
#pragma unroll
      for (int r = 0; r < 4; ++r) {
        int row = row0 + r;
        if (row >= M) continue;
        float v = acc[m][n][r];
        if (BIAS) v += bias[col];
        if (ADDC) v += addC[(size_t)row * N + col];
        if (ACT == 1) v = fmaxf(v, 0.f);
        if (ACT == 2) v = gelu_exact(v);
        if (OUT_BF16)
          ((bf16*)Cout)[(size_t)row * N + col] = __float2bfloat16(v);
        else
          ((float*)Cout)[(size_t)row * N + col] = v;
        if (HBF)
          out2[(size_t)row * N + col] = __float2bfloat16(v);
      }
    }
  }
}

template <int NWM, int NWN, int KCHUNK, int ACT, int OUT_BF16, int ADDC, int BIAS, int HBF>
static void launch_bpanel(const bf16* A, const bf16* W, const float* bias,
                          const float* addC, void* C, bf16* out2,
                          int M, int N, int K, hipStream_t stream) {
  dim3 grid(M / (NWM * 64), (N + 63) / 64);
  gemm_bpanel_kernel<NWM, NWN, KCHUNK, ACT, OUT_BF16, ADDC, BIAS, HBF, 0>
      <<<grid, 256, 0, stream>>>(A, W, bias, addC, C, out2, M, N, K, 0);
}

// ---------------- launch ----------------

#define MB (1024u * 1024u)

extern "C" void kernel_launch(void* const* d_in, const int* in_sizes, int n_in,
                              void* d_out, int out_size, void* d_ws, size_t ws_size,
                              hipStream_t stream) {
  const int*   node_indices = (const int*)d_in[0];
  const int*   edge_index   = (const int*)d_in[1];
  const float* edge_weight  = (const float*)d_in[2];
  const float* cache        = (const float*)d_in[3];
  const float* w_root       = (const float*)d_in[4];
  const float* w_neigh      = (const float*)d_in[5];
  const float* w_post       = (const float*)d_in[6];
  const float* b_post       = (const float*)d_in[7];
  const float* fallback     = (const float*)d_in[8];
  const float* ln_in_scale  = (const float*)d_in[9];
  const float* ln_in_bias   = (const float*)d_in[10];
  const float* w_in         = (const float*)d_in[11];
  const float* rb_ln_scale  = (const float*)d_in[12];
  const float* rb_ln_bias   = (const float*)d_in[13];
  const float* rb_fc1       = (const float*)d_in[14];
  const float* rb_fc2       = (const float*)d_in[15];
  const float* w_bil        = (const float*)d_in[16];
  const float* gene         = (const float*)d_in[17];
  float* out = (float*)d_out;

  char* w = (char*)d_ws;
  // --- region A (0..24 MB): graph-stage buffers, dead after gather_ln; ymid aliases ---
  bf16*  compact2 = (bf16*)(w + 0 * MB);   // 4 MB
  bf16*  tmpc     = (bf16*)(w + 4 * MB);   // 2 MB
  float* embc     = (float*)(w + 6 * MB);  // 4 MB
  int*   el_src   = (int*)  (w + 10 * MB); // 2 MB
  float* el_w     = (float*)(w + 12 * MB); // 2 MB
  int*   flags    = (int*)  (w + 14 * MB);
  int*   slot     = (int*)  (w + 14 * MB + 80 * 1024);
  int*   uniq     = (int*)  (w + 14 * MB + 160 * 1024);
  int*   cursor   = (int*)  (w + 14 * MB + 180 * 1024);
  int*   nuniq    = (int*)  (w + 14 * MB + 200 * 1024);
  bf16*  ymid     = (bf16*) (w + 0 * MB);  // 16 MB (phase-4 only, region A dead)
  // --- region B (24 MB..): activations + bf16 weights ---
  bf16*  pertln  = (bf16*) (w + 24 * MB);
  float* h       = (float*)(w + 26 * MB);
  bf16*  yln     = (bf16*) (w + 34 * MB);
  bf16*  h_bf    = (bf16*) (w + 38 * MB);
  bf16*  blin    = (bf16*) (w + 42 * MB);
  bf16*  w_in_bf = (bf16*) (w + 55 * MB);
  bf16*  fc1_bf  = (bf16*) (w + 56 * MB);
  bf16*  fc2_bf  = (bf16*) (w + 68 * MB);
  bf16*  wbil_bf = (bf16*) (w + 80 * MB);
  bf16*  gene_bf = (bf16*) (w + 82 * MB);
  bf16*  wrn_bf  = (bf16*) (w + 90 * MB);
  bf16*  wpost_bf= (bf16*) (w + 91 * MB);

  // 0) all weight conversions in ONE kernel
  convert_weights_kernel<<<(CONV_TOT + 255) / 256, 256, 0, stream>>>(
      w_in, rb_fc1, rb_fc2, w_bil, gene, w_post, w_root, w_neigh,
      w_in_bf, fc1_bf, fc2_bf, wbil_bf, gene_bf, wpost_bf, wrn_bf);

  // 1) compact-slot construction + bucketed edge lists + gather-accumulate (bf16 out)
  init_meta_kernel<<<(N_NODES + 255) / 256, 256, 0, stream>>>(flags, cursor, nuniq);
  mark_needed_kernel<<<(BATCH + 255) / 256, 256, 0, stream>>>(node_indices, flags);
  assign_slots_kernel<<<(N_NODES + 255) / 256, 256, 0, stream>>>(flags, slot, uniq, nuniq);
  fill_edges_kernel<<<(N_EDGES + 255) / 256, 256, 0, stream>>>(
      edge_index, edge_weight, flags, slot, cursor, el_src, el_w);
  gather_nodes_kernel<<<BATCH, 256, 0, stream>>>(
      cache, uniq, cursor, nuniq, el_src, el_w, compact2);

  // 2) compact graph tail: relu([cache|agg]@[wr|wn]^T) @ w_post^T + b
  launch_bpanel<4, 1, 512, 1, 1, 0, 0, 0>(compact2, wrn_bf, nullptr, nullptr, tmpc, nullptr,
                                          BATCH, GNN_D, 2 * GNN_D, stream);
  launch_bpanel<4, 1, 256, 0, 0, 0, 1, 0>(tmpc, wpost_bf, b_post, nullptr, embc, nullptr,
                                          BATCH, GNN_D, GNN_D, stream);

  // 3) gather + input LN (bf16 out), input proj -> h fp32
  gather_ln_kernel<<<BATCH, 256, 0, stream>>>(embc, slot, fallback, node_indices,
                                              ln_in_scale, ln_in_bias, pertln);
  launch_bpanel<4, 1, 256, 0, 0, 0, 0, 0>(pertln, w_in_bf, nullptr, nullptr, h, nullptr,
                                          BATCH, H_D, GNN_D, stream);

  // 4) residual blocks: LN -> fc1(gelu, bf16) -> fc2(+h, fp32; K=2048 via 4 chunks)
  for (int i = 0; i < L_N; ++i) {
    ln512_kernel<<<BATCH, 256, 0, stream>>>(h, rb_ln_scale + (size_t)i * H_D,
                                            rb_ln_bias + (size_t)i * H_D, yln);
    launch_bpanel<4, 1, 512, 2, 1, 0, 0, 0>(yln, fc1_bf + (size_t)i * MID_D * H_D,
                                            nullptr, nullptr, ymid, nullptr,
                                            BATCH, MID_D, H_D, stream);
    if (i < L_N - 1)
      launch_bpanel<2, 2, 512, 0, 0, 1, 0, 0>(ymid, fc2_bf + (size_t)i * H_D * MID_D,
                                              nullptr, h, h, nullptr,
                                              BATCH, H_D, MID_D, stream);
    else
      launch_bpanel<2, 2, 512, 0, 0, 1, 0, 1>(ymid, fc2_bf + (size_t)i * H_D * MID_D,
                                              nullptr, h, h, h_bf,
                                              BATCH, H_D, MID_D, stream);
  }

  // 5) bilinear head (bf16 out) + gene einsum (fp32 out, XCD-swizzled 1D grid)
  launch_bpanel<4, 1, 512, 0, 1, 0, 0, 0>(h_bf, wbil_bf, nullptr, nullptr, blin, nullptr,
                                          BATCH, C_N * R_D, H_D, stream);
  {
    int gx = (BATCH * C_N) / 256;            // 48
    int gy = (G_N + 63) / 64;                // 104
    int nwg = gx * gy;                       // 4992 (divisible by 8)
    gemm_bpanel_kernel<4, 1, 512, 0, 0, 0, 0, 0, 1><<<nwg, 256, 0, stream>>>(
        blin, gene_bf, nullptr, nullptr, out, nullptr, BATCH * C_N, G_N, R_D, gx);
  }
}

// Round 7
// 625.593 us; speedup vs baseline: 1.3793x; 1.3793x over previous
//
#include <hip/hip_runtime.h>
#include <hip/hip_bf16.h>

#define N_NODES 19000
#define N_EDGES 600000
#define BATCH   4096
#define GNN_D   256
#define H_D     512
#define MID_D   2048
#define L_N     6
#define C_N     3
#define R_D     512
#define G_N     6640
#define LN_EPS  1e-5f
#define MAXDEG  128

typedef __attribute__((ext_vector_type(8))) short short8;
typedef __attribute__((ext_vector_type(4))) float f32x4;
typedef __hip_bfloat16 bf16;

// ---------------- merged weight conversion (7 dsts, 1 launch) ----------------
#define SEG0 32768                    // w_in   512*256/4
#define SEG1 (SEG0 + 1572864)         // fc1    6*2048*512/4
#define SEG2 (SEG1 + 1572864)         // fc2
#define SEG3 (SEG2 + 196608)          // wbil   3*512*512/4
#define SEG4 (SEG3 + 849920)          // gene   6640*512/4
#define SEG5 (SEG4 + 16384)           // wpost  256*256/4
#define SEG6 (SEG5 + 32768)           // wrn    256*512/4
#define CONV_TOT SEG6

__global__ void convert_weights_kernel(
    const float* __restrict__ w_in, const float* __restrict__ fc1,
    const float* __restrict__ fc2, const float* __restrict__ wbil,
    const float* __restrict__ gene, const float* __restrict__ wpost,
    const float* __restrict__ wroot, const float* __restrict__ wneigh,
    bf16* __restrict__ o_win, bf16* __restrict__ o_fc1, bf16* __restrict__ o_fc2,
    bf16* __restrict__ o_wbil, bf16* __restrict__ o_gene, bf16* __restrict__ o_wpost,
    bf16* __restrict__ o_wrn) {
  int i = blockIdx.x * blockDim.x + threadIdx.x;
  if (i >= CONV_TOT) return;
  const float* src;
  bf16* dst;
  if (i < SEG0)      { src = w_in  + (size_t)i * 4;            dst = o_win  + (size_t)i * 4; }
  else if (i < SEG1) { size_t j = i - SEG0; src = fc1  + j * 4; dst = o_fc1  + j * 4; }
  else if (i < SEG2) { size_t j = i - SEG1; src = fc2  + j * 4; dst = o_fc2  + j * 4; }
  else if (i < SEG3) { size_t j = i - SEG2; src = wbil + j * 4; dst = o_wbil + j * 4; }
  else if (i < SEG4) { size_t j = i - SEG3; src = gene + j * 4; dst = o_gene + j * 4; }
  else if (i < SEG5) { size_t j = i - SEG4; src = wpost+ j * 4; dst = o_wpost+ j * 4; }
  else {  // wrn: [256][512] = [w_root | w_neigh]
    int j = i - SEG5;
    int base = j * 4;
    int n = base >> 9;
    int k = base & 511;
    src = (k < GNN_D) ? (wroot + (size_t)n * GNN_D + k)
                      : (wneigh + (size_t)n * GNN_D + (k - GNN_D));
    dst = o_wrn + base;
  }
  float4 v = *(const float4*)src;
  dst[0] = __float2bfloat16(v.x);
  dst[1] = __float2bfloat16(v.y);
  dst[2] = __float2bfloat16(v.z);
  dst[3] = __float2bfloat16(v.w);
}

// ---------------- graph compaction kernels (unchanged, proven) ----------------

__global__ void init_meta_kernel(int* __restrict__ flags, int* __restrict__ cursor,
                                 int* __restrict__ nuniq) {
  int i = blockIdx.x * blockDim.x + threadIdx.x;
  if (i < N_NODES) flags[i] = 0;
  if (i < BATCH) cursor[i] = 0;
  if (i == 0) *nuniq = 0;
}

__global__ void mark_needed_kernel(const int* __restrict__ idx, int* __restrict__ flags) {
  int i = blockIdx.x * blockDim.x + threadIdx.x;
  if (i < BATCH) {
    int id = idx[i];
    if (id >= 0) flags[id] = 1;
  }
}

__global__ void assign_slots_kernel(const int* __restrict__ flags, int* __restrict__ slot,
                                    int* __restrict__ uniq, int* __restrict__ nuniq) {
  int i = blockIdx.x * blockDim.x + threadIdx.x;
  if (i >= N_NODES) return;
  if (flags[i]) {
    int s = atomicAdd(nuniq, 1);
    slot[i] = s;
    uniq[s] = i;
  }
}

__global__ __launch_bounds__(256) void fill_edges_kernel(
    const int* __restrict__ ei, const float* __restrict__ ew,
    const int* __restrict__ flags, const int* __restrict__ slot,
    int* __restrict__ cursor, int* __restrict__ el_src, float* __restrict__ el_w) {
  int e = blockIdx.x * blockDim.x + threadIdx.x;
  if (e >= N_EDGES) return;
  int dst = ei[N_EDGES + e];
  if (!flags[dst]) return;
  int s = slot[dst];
  int p = atomicAdd(&cursor[s], 1);
  if (p < MAXDEG) {
    el_src[s * MAXDEG + p] = ei[e];
    el_w[s * MAXDEG + p] = ew[e];
  }
}

__global__ __launch_bounds__(256) void gather_nodes_kernel(
    const float* __restrict__ cache, const int* __restrict__ uniq,
    const int* __restrict__ cursor, const int* __restrict__ nuniq,
    const int* __restrict__ el_src, const float* __restrict__ el_w,
    bf16* __restrict__ compact2) {
  int s = blockIdx.x, t = threadIdx.x;
  bf16* row = compact2 + (size_t)s * (2 * GNN_D);
  if (s >= *nuniq) {
    row[t] = __float2bfloat16(0.f);
    row[GNN_D + t] = __float2bfloat16(0.f);
    return;
  }
  row[t] = __float2bfloat16(cache[(size_t)uniq[s] * GNN_D + t]);
  int deg = cursor[s];
  deg = (deg < MAXDEG) ? deg : MAXDEG;
  float acc = 0.f;
  for (int e = 0; e < deg; ++e) {
    int src = el_src[s * MAXDEG + e];
    float w = el_w[s * MAXDEG + e];
    acc += cache[(size_t)src * GNN_D + t] * w;
  }
  row[GNN_D + t] = __float2bfloat16(acc);
}

__global__ __launch_bounds__(256) void gather_ln_kernel(
    const float* __restrict__ embc, const int* __restrict__ slot,
    const float* __restrict__ fallback, const int* __restrict__ idx,
    const float* __restrict__ scale, const float* __restrict__ bias,
    bf16* __restrict__ out) {
  int b = blockIdx.x, t = threadIdx.x;
  int id = idx[b];
  float v = (id >= 0) ? embc[(size_t)slot[id] * GNN_D + t] : fallback[t];
  float s = v, q = v * v;
#pragma unroll
  for (int o = 32; o > 0; o >>= 1) { s += __shfl_down(s, o); q += __shfl_down(q, o); }
  __shared__ float ls[4], lq[4];
  int wv = t >> 6, ln = t & 63;
  if (ln == 0) { ls[wv] = s; lq[wv] = q; }
  __syncthreads();
  s = ls[0] + ls[1] + ls[2] + ls[3];
  q = lq[0] + lq[1] + lq[2] + lq[3];
  float mu = s * (1.f / GNN_D);
  float var = q * (1.f / GNN_D) - mu * mu;
  float r = rsqrtf(var + LN_EPS);
  out[(size_t)b * GNN_D + t] = __float2bfloat16((v - mu) * r * scale[t] + bias[t]);
}

__global__ __launch_bounds__(256) void ln512_kernel(
    const float* __restrict__ x, const float* __restrict__ scale,
    const float* __restrict__ bias, bf16* __restrict__ out) {
  int b = blockIdx.x, t = threadIdx.x;
  const float* xr = x + (size_t)b * H_D;
  float v0 = xr[t];
  float v1 = xr[256 + t];
  float s = v0 + v1, q = v0 * v0 + v1 * v1;
#pragma unroll
  for (int o = 32; o > 0; o >>= 1) { s += __shfl_down(s, o); q += __shfl_down(q, o); }
  __shared__ float ls[4], lq[4];
  int wv = t >> 6, ln = t & 63;
  if (ln == 0) { ls[wv] = s; lq[wv] = q; }
  __syncthreads();
  s = ls[0] + ls[1] + ls[2] + ls[3];
  q = lq[0] + lq[1] + lq[2] + lq[3];
  float mu = s * (1.f / H_D);
  float var = q * (1.f / H_D) - mu * mu;
  float r = rsqrtf(var + LN_EPS);
  bf16* orow = out + (size_t)b * H_D;
  orow[t]       = __float2bfloat16((v0 - mu) * r * scale[t]       + bias[t]);
  orow[256 + t] = __float2bfloat16((v1 - mu) * r * scale[256 + t] + bias[256 + t]);
}

__device__ inline float gelu_exact(float x) {
  return 0.5f * x * (1.f + erff(x * 0.70710678118654752f));
}

// ---------------- bf16 MFMA GEMM: C = act(A @ W^T [+ bias] [+ addC]) ----------------
// Round-4 proven structure, generalized wave grid. A:[M,K], W:[N,K] bf16 row-major.
// BM=NBM*64, BN=NBN*64; WR x WC waves (THREADS = WR*WC*64); wave owns (BM/WR)x(BN/WC).
// 2-phase double-buffered K-loop: issue next-tile global_load_lds into buf^1 BEFORE
// ds_read+MFMA of buf; single vmcnt(0)+barrier per K-step (__syncthreads).

template <int WR, int WC, int NBM, int NBN, int ACT, int OUT_BF16, int ADDC, int BIAS,
          int HBF, int SWZ>
__global__ __launch_bounds__(WR * WC * 64) void gemm_mfma_kernel(
    const bf16* __restrict__ A, const bf16* __restrict__ W,
    const float* __restrict__ bias, const float* __restrict__ addC,
    void* __restrict__ Cout, bf16* __restrict__ out2,
    int M, int N, int K, int gx) {
  constexpr int THREADS = WR * WC * 64;
  constexpr int BM = NBM * 64;
  constexpr int BN = NBN * 64;
  constexpr int MR = BM / (WR * 16);   // m-frags per wave
  constexpr int NR = BN / (WC * 16);   // n-frags per wave
  constexpr int ITA = (BM * 4) / THREADS;  // A staging iters (16B chunks)
  constexpr int ITB = (BN * 4) / THREADS;
  __shared__ __align__(16) bf16 sA[2][BM * 32];
  __shared__ __align__(16) bf16 sB[2][BN * 32];
  const int tid = threadIdx.x;
  const int lane = tid & 63;
  const int wid = tid >> 6;
  const int wr = wid / WC, wc = wid % WC;

  int bidx, bidy;
  if (SWZ) {
    // chunked XCD map (nwg % 8 == 0): each XCD gets a contiguous chunk;
    // bidx (M) varies fastest within the chunk -> B-panel stays L2-resident.
    int nwg = gridDim.x;
    int bid = blockIdx.x;
    int l = (bid & 7) * (nwg >> 3) + (bid >> 3);
    bidx = l % gx;
    bidy = l / gx;
  } else {
    bidx = blockIdx.x;
    bidy = blockIdx.y;
  }
  const int bm = bidx * BM, bn = bidy * BN;

  f32x4 acc[MR][NR];
#pragma unroll
  for (int m = 0; m < MR; ++m)
#pragma unroll
    for (int n = 0; n < NR; ++n) acc[m][n] = (f32x4){0.f, 0.f, 0.f, 0.f};

  const int rbase = lane & 15;
  const int g = lane >> 4;
  const int kq = (tid & 3) << 3;    // per-thread k offset within 32-chunk

  int arow[ITA], brow[ITB];
#pragma unroll
  for (int i = 0; i < ITA; ++i) {
    int r0 = bm + ((i * THREADS + tid) >> 2);
    arow[i] = (r0 < M) ? r0 : (M - 1);
  }
#pragma unroll
  for (int i = 0; i < ITB; ++i) {
    int r0 = bn + ((i * THREADS + tid) >> 2);
    brow[i] = (r0 < N) ? r0 : (N - 1);
  }

  auto stage = [&](int buf, int k0) {
#pragma unroll
    for (int i = 0; i < ITA; ++i)
      __builtin_amdgcn_global_load_lds(
          (const __attribute__((address_space(1))) void*)(A + (size_t)arow[i] * K + k0 + kq),
          (__attribute__((address_space(3))) void*)(&sA[buf][(i * THREADS + tid) * 8]), 16, 0, 0);
#pragma unroll
    for (int i = 0; i < ITB; ++i)
      __builtin_amdgcn_global_load_lds(
          (const __attribute__((address_space(1))) void*)(W + (size_t)brow[i] * K + k0 + kq),
          (__attribute__((address_space(3))) void*)(&sB[buf][(i * THREADS + tid) * 8]), 16, 0, 0);
  };

  const int NT = K >> 5;
  stage(0, 0);
  __syncthreads();               // drain prologue stage

  int cur = 0;
  for (int t = 0; t < NT; ++t) {
    if (t + 1 < NT) stage(cur ^ 1, (t + 1) << 5);   // issue next tile early

    short8 af[MR], bfrag[NR];
#pragma unroll
    for (int m = 0; m < MR; ++m)
      af[m] = *(const short8*)(&sA[cur][(wr * (BM / WR) + m * 16 + rbase) * 32 + g * 8]);
#pragma unroll
    for (int n = 0; n < NR; ++n)
      bfrag[n] = *(const short8*)(&sB[cur][(wc * (BN / WC) + n * 16 + rbase) * 32 + g * 8]);
#pragma unroll
    for (int m = 0; m < MR; ++m)
#pragma unroll
      for (int n = 0; n < NR; ++n)
        acc[m][n] = __builtin_amdgcn_mfma_f32_16x16x32_bf16(af[m], bfrag[n], acc[m][n], 0, 0, 0);

    __syncthreads();             // one vmcnt(0)+barrier per K-step
    cur ^= 1;
  }

  // C/D frag mapping: col = lane&15, row = (lane>>4)*4 + reg   [m89-verified]
  const int rb = (lane >> 4) * 4;
  const int cb = lane & 15;
#pragma unroll
  for (int m = 0; m < MR; ++m) {
#pragma unroll
    for (int n = 0; n < NR; ++n) {
      int col = bn + wc * (BN / WC) + n * 16 + cb;
      if (col >= N) continue;
      int row0 = bm + wr * (BM / WR) + m * 16 + rb;
#pragma unroll
      for (int r = 0; r < 4; ++r) {
        int row = row0 + r;
        if (row >= M) continue;
        float v = acc[m][n][r];
        if (BIAS) v += bias[col];
        if (ADDC) v += addC[(size_t)row * N + col];
        if (ACT == 1) v = fmaxf(v, 0.f);
        if (ACT == 2) v = gelu_exact(v);
        if (OUT_BF16)
          ((bf16*)Cout)[(size_t)row * N + col] = __float2bfloat16(v);
        else
          ((float*)Cout)[(size_t)row * N + col] = v;
        if (HBF)
          out2[(size_t)row * N + col] = __float2bfloat16(v);
      }
    }
  }
}

template <int WR, int WC, int NBM, int NBN, int ACT, int OUT_BF16, int ADDC, int BIAS, int HBF>
static void launch_mfma(const bf16* A, const bf16* W, const float* bias,
                        const float* addC, void* C, bf16* out2,
                        int M, int N, int K, hipStream_t stream) {
  dim3 grid(M / (NBM * 64), (N + NBN * 64 - 1) / (NBN * 64));
  gemm_mfma_kernel<WR, WC, NBM, NBN, ACT, OUT_BF16, ADDC, BIAS, HBF, 0>
      <<<grid, WR * WC * 64, 0, stream>>>(A, W, bias, addC, C, out2, M, N, K, 0);
}

// ---------------- launch ----------------

#define MB (1024u * 1024u)

extern "C" void kernel_launch(void* const* d_in, const int* in_sizes, int n_in,
                              void* d_out, int out_size, void* d_ws, size_t ws_size,
                              hipStream_t stream) {
  const int*   node_indices = (const int*)d_in[0];
  const int*   edge_index   = (const int*)d_in[1];
  const float* edge_weight  = (const float*)d_in[2];
  const float* cache        = (const float*)d_in[3];
  const float* w_root       = (const float*)d_in[4];
  const float* w_neigh      = (const float*)d_in[5];
  const float* w_post       = (const float*)d_in[6];
  const float* b_post       = (const float*)d_in[7];
  const float* fallback     = (const float*)d_in[8];
  const float* ln_in_scale  = (const float*)d_in[9];
  const float* ln_in_bias   = (const float*)d_in[10];
  const float* w_in         = (const float*)d_in[11];
  const float* rb_ln_scale  = (const float*)d_in[12];
  const float* rb_ln_bias   = (const float*)d_in[13];
  const float* rb_fc1       = (const float*)d_in[14];
  const float* rb_fc2       = (const float*)d_in[15];
  const float* w_bil        = (const float*)d_in[16];
  const float* gene         = (const float*)d_in[17];
  float* out = (float*)d_out;

  char* w = (char*)d_ws;
  // --- region A (0..24 MB): graph-stage buffers, dead after gather_ln; ymid aliases ---
  bf16*  compact2 = (bf16*)(w + 0 * MB);   // 4 MB
  bf16*  tmpc     = (bf16*)(w + 4 * MB);   // 2 MB
  float* embc     = (float*)(w + 6 * MB);  // 4 MB
  int*   el_src   = (int*)  (w + 10 * MB); // 2 MB
  float* el_w     = (float*)(w + 12 * MB); // 2 MB
  int*   flags    = (int*)  (w + 14 * MB);
  int*   slot     = (int*)  (w + 14 * MB + 80 * 1024);
  int*   uniq     = (int*)  (w + 14 * MB + 160 * 1024);
  int*   cursor   = (int*)  (w + 14 * MB + 180 * 1024);
  int*   nuniq    = (int*)  (w + 14 * MB + 200 * 1024);
  bf16*  ymid     = (bf16*) (w + 0 * MB);  // 16 MB (phase-4 only, region A dead)
  // --- region B (24 MB..): activations + bf16 weights ---
  bf16*  pertln  = (bf16*) (w + 24 * MB);
  float* h       = (float*)(w + 26 * MB);
  bf16*  yln     = (bf16*) (w + 34 * MB);
  bf16*  h_bf    = (bf16*) (w + 38 * MB);
  bf16*  blin    = (bf16*) (w + 42 * MB);
  bf16*  w_in_bf = (bf16*) (w + 55 * MB);
  bf16*  fc1_bf  = (bf16*) (w + 56 * MB);
  bf16*  fc2_bf  = (bf16*) (w + 68 * MB);
  bf16*  wbil_bf = (bf16*) (w + 80 * MB);
  bf16*  gene_bf = (bf16*) (w + 82 * MB);
  bf16*  wrn_bf  = (bf16*) (w + 90 * MB);
  bf16*  wpost_bf= (bf16*) (w + 91 * MB);

  // 0) all weight conversions in ONE kernel
  convert_weights_kernel<<<(CONV_TOT + 255) / 256, 256, 0, stream>>>(
      w_in, rb_fc1, rb_fc2, w_bil, gene, w_post, w_root, w_neigh,
      w_in_bf, fc1_bf, fc2_bf, wbil_bf, gene_bf, wpost_bf, wrn_bf);

  // 1) compact-slot construction + bucketed edge lists + gather-accumulate (bf16 out)
  init_meta_kernel<<<(N_NODES + 255) / 256, 256, 0, stream>>>(flags, cursor, nuniq);
  mark_needed_kernel<<<(BATCH + 255) / 256, 256, 0, stream>>>(node_indices, flags);
  assign_slots_kernel<<<(N_NODES + 255) / 256, 256, 0, stream>>>(flags, slot, uniq, nuniq);
  fill_edges_kernel<<<(N_EDGES + 255) / 256, 256, 0, stream>>>(
      edge_index, edge_weight, flags, slot, cursor, el_src, el_w);
  gather_nodes_kernel<<<BATCH, 256, 0, stream>>>(
      cache, uniq, cursor, nuniq, el_src, el_w, compact2);

  // 2) compact graph tail (bf16 MFMA, 64x64): relu([cache|agg]@[wr|wn]^T) @ w_post^T + b
  launch_mfma<2, 2, 1, 1, 1, 1, 0, 0, 0>(compact2, wrn_bf, nullptr, nullptr, tmpc, nullptr,
                                         BATCH, GNN_D, 2 * GNN_D, stream);
  launch_mfma<2, 2, 1, 1, 0, 0, 0, 1, 0>(tmpc, wpost_bf, b_post, nullptr, embc, nullptr,
                                         BATCH, GNN_D, GNN_D, stream);

  // 3) gather + input LN (bf16 out), input proj (64x64) -> h fp32
  gather_ln_kernel<<<BATCH, 256, 0, stream>>>(embc, slot, fallback, node_indices,
                                              ln_in_scale, ln_in_bias, pertln);
  launch_mfma<2, 2, 1, 1, 0, 0, 0, 0, 0>(pertln, w_in_bf, nullptr, nullptr, h, nullptr,
                                         BATCH, H_D, GNN_D, stream);

  // 4) residual blocks: LN -> fc1(gelu, bf16, 128x128) -> fc2(+h, fp32, 64x64)
  for (int i = 0; i < L_N; ++i) {
    ln512_kernel<<<BATCH, 256, 0, stream>>>(h, rb_ln_scale + (size_t)i * H_D,
                                            rb_ln_bias + (size_t)i * H_D, yln);
    launch_mfma<2, 2, 2, 2, 2, 1, 0, 0, 0>(yln, fc1_bf + (size_t)i * MID_D * H_D,
                                           nullptr, nullptr, ymid, nullptr,
                                           BATCH, MID_D, H_D, stream);
    if (i < L_N - 1)
      launch_mfma<2, 2, 1, 1, 0, 0, 1, 0, 0>(ymid, fc2_bf + (size_t)i * H_D * MID_D,
                                             nullptr, h, h, nullptr,
                                             BATCH, H_D, MID_D, stream);
    else  // last layer: also emit bf16 h for the bilinear head
      launch_mfma<2, 2, 1, 1, 0, 0, 1, 0, 1>(ymid, fc2_bf + (size_t)i * H_D * MID_D,
                                             nullptr, h, h, h_bf,
                                             BATCH, H_D, MID_D, stream);
  }

  // 5) bilinear head (64x128, bf16 out) + gene einsum (8-wave 256x256, fp32 out,
  //    chunked-XCD 1D grid: bidx fast within each XCD chunk)
  launch_mfma<2, 2, 1, 2, 0, 1, 0, 0, 0>(h_bf, wbil_bf, nullptr, nullptr, blin, nullptr,
                                         BATCH, C_N * R_D, H_D, stream);
  {
    int gx = (BATCH * C_N) / 256;            // 48
    int gy = (G_N + 255) / 256;              // 26
    int nwg = gx * gy;                       // 1248 (divisible by 8)
    gemm_mfma_kernel<2, 4, 4, 4, 0, 0, 0, 0, 0, 1><<<nwg, 512, 0, stream>>>(
        blin, gene_bf, nullptr, nullptr, out, nullptr, BATCH * C_N, G_N, R_D, gx);
  }
}